// Round 1
// baseline (1174.056 us; speedup 1.0000x reference)
//
#include <hip/hip_runtime.h>
#include <hip/hip_bf16.h>
#include <math.h>

#define EMBED 384
#define HD 64
#define QBLK 64   // q rows per attn block
#define KBLK 32   // keys per LDS tile
#define PROJ_ROWS 16  // x rows per projection block

// ---------------- Projection: k,q,v = x @ {Wk,Wq,Wv} ----------------
// block 256 threads: thread = (row-group rg=tid>>6 -> 4 rows, h = tid&63)
__global__ __launch_bounds__(256) void qkv_proj(
    const float* __restrict__ x,
    const float* __restrict__ Wk, const float* __restrict__ Wq,
    const float* __restrict__ Wv,
    float* __restrict__ kout, float* __restrict__ qout, float* __restrict__ vout)
{
    __shared__ float xs[PROJ_ROWS * EMBED];   // 24 KB
    const int base = blockIdx.x * PROJ_ROWS;
    // stage 16 contiguous rows of x
    const float4* xsrc = (const float4*)(x + (size_t)base * EMBED);
    for (int i = threadIdx.x; i < PROJ_ROWS * EMBED / 4; i += 256)
        ((float4*)xs)[i] = xsrc[i];
    __syncthreads();

    const int h  = threadIdx.x & 63;
    const int rg = threadIdx.x >> 6;          // 0..3, rows rg*4 .. rg*4+3
    float ak[4] = {0,0,0,0}, aq[4] = {0,0,0,0}, av[4] = {0,0,0,0};
    const float4* xr = (const float4*)(xs + rg * 4 * EMBED);

    #pragma unroll 2
    for (int c4 = 0; c4 < EMBED / 4; ++c4) {
        float4 xv[4];
        #pragma unroll
        for (int r = 0; r < 4; ++r) xv[r] = xr[r * (EMBED/4) + c4];
        const int c = c4 * 4;
        #pragma unroll
        for (int cc = 0; cc < 4; ++cc) {
            const float wk = Wk[(c + cc) * HD + h];
            const float wq = Wq[(c + cc) * HD + h];
            const float wv = Wv[(c + cc) * HD + h];
            #pragma unroll
            for (int r = 0; r < 4; ++r) {
                const float xvv = (cc == 0) ? xv[r].x : (cc == 1) ? xv[r].y
                                : (cc == 2) ? xv[r].z : xv[r].w;
                ak[r] = fmaf(xvv, wk, ak[r]);
                aq[r] = fmaf(xvv, wq, aq[r]);
                av[r] = fmaf(xvv, wv, av[r]);
            }
        }
    }
    const float qscale = 0.051031036307982884f;  // 1/sqrt(384)
    #pragma unroll
    for (int r = 0; r < 4; ++r) {
        const size_t row = (size_t)base + rg * 4 + r;
        kout[row * HD + h] = ak[r];
        qout[row * HD + h] = aq[r] * qscale;
        vout[row * HD + h] = av[r];
    }
}

// ---------------- Flash attention (causal), f32 VALU ----------------
// grid: (T/QBLK, B). block 256 = 4 waves; wave handles 16 q rows.
// lane -> (row = lane&15, d-chunk = (lane>>4)*16)
__global__ __launch_bounds__(256) void attn(
    const float* __restrict__ kin, const float* __restrict__ qin,
    const float* __restrict__ vin, float* __restrict__ out, int T)
{
    __shared__ float ks[KBLK * HD];  // 8 KB
    __shared__ float vs[KBLK * HD];  // 8 KB

    const int b     = blockIdx.y;
    const int qtile = gridDim.x - 1 - blockIdx.x;   // heaviest blocks first
    const int qstart = qtile * QBLK;
    const int wave = threadIdx.x >> 6;
    const int lane = threadIdx.x & 63;
    const int rloc = (wave << 4) | (lane & 15);
    const int dq   = (lane >> 4) << 4;              // 0,16,32,48
    const int rg   = qstart + rloc;                 // global q row

    const float4* qrow = (const float4*)(qin + ((size_t)b * T + rg) * HD + dq);
    const float4 q0 = qrow[0], q1 = qrow[1], q2 = qrow[2], q3 = qrow[3];

    float m = -INFINITY, lsum = 0.f;
    float4 o0 = {0,0,0,0}, o1 = {0,0,0,0}, o2 = {0,0,0,0}, o3 = {0,0,0,0};

    const int nk = qstart + QBLK;   // causal: keys [0, nk)
    for (int kst = 0; kst < nk; kst += KBLK) {
        __syncthreads();
        const float4* ksrc = (const float4*)(kin + ((size_t)b * T + kst) * HD);
        const float4* vsrc = (const float4*)(vin + ((size_t)b * T + kst) * HD);
        for (int i = threadIdx.x; i < KBLK * HD / 4; i += 256) {
            ((float4*)ks)[i] = ksrc[i];
            ((float4*)vs)[i] = vsrc[i];
        }
        __syncthreads();

        #pragma unroll 4
        for (int j = 0; j < KBLK; ++j) {
            const float4* kr = (const float4*)(ks + j * HD + dq);
            const float4 k0 = kr[0], k1 = kr[1], k2 = kr[2], k3 = kr[3];
            float a0 = q0.x*k0.x + q0.y*k0.y + q0.z*k0.z + q0.w*k0.w;
            float a1 = q1.x*k1.x + q1.y*k1.y + q1.z*k1.z + q1.w*k1.w;
            float a2 = q2.x*k2.x + q2.y*k2.y + q2.z*k2.z + q2.w*k2.w;
            float a3 = q3.x*k3.x + q3.y*k3.y + q3.z*k3.z + q3.w*k3.w;
            float s = (a0 + a1) + (a2 + a3);
            s += __shfl_xor(s, 16);
            s += __shfl_xor(s, 32);
            s = (kst + j <= rg) ? s : -INFINITY;   // causal mask

            // deferred-rescale online softmax (THR=8)
            if (!__all(s - m <= 8.0f)) {
                const float mn = fmaxf(m, s);
                const float corr = __expf(m - mn);
                lsum *= corr;
                o0.x *= corr; o0.y *= corr; o0.z *= corr; o0.w *= corr;
                o1.x *= corr; o1.y *= corr; o1.z *= corr; o1.w *= corr;
                o2.x *= corr; o2.y *= corr; o2.z *= corr; o2.w *= corr;
                o3.x *= corr; o3.y *= corr; o3.z *= corr; o3.w *= corr;
                m = mn;
            }
            const float p = __expf(s - m);
            lsum += p;
            const float4* vr = (const float4*)(vs + j * HD + dq);
            const float4 v0 = vr[0], v1 = vr[1], v2 = vr[2], v3 = vr[3];
            o0.x = fmaf(p, v0.x, o0.x); o0.y = fmaf(p, v0.y, o0.y);
            o0.z = fmaf(p, v0.z, o0.z); o0.w = fmaf(p, v0.w, o0.w);
            o1.x = fmaf(p, v1.x, o1.x); o1.y = fmaf(p, v1.y, o1.y);
            o1.z = fmaf(p, v1.z, o1.z); o1.w = fmaf(p, v1.w, o1.w);
            o2.x = fmaf(p, v2.x, o2.x); o2.y = fmaf(p, v2.y, o2.y);
            o2.z = fmaf(p, v2.z, o2.z); o2.w = fmaf(p, v2.w, o2.w);
            o3.x = fmaf(p, v3.x, o3.x); o3.y = fmaf(p, v3.y, o3.y);
            o3.z = fmaf(p, v3.z, o3.z); o3.w = fmaf(p, v3.w, o3.w);
        }
    }

    const float inv = 1.f / lsum;
    float4* op = (float4*)(out + ((size_t)b * T + rg) * HD + dq);
    float4 w0 = {o0.x*inv, o0.y*inv, o0.z*inv, o0.w*inv};
    float4 w1 = {o1.x*inv, o1.y*inv, o1.z*inv, o1.w*inv};
    float4 w2 = {o2.x*inv, o2.y*inv, o2.z*inv, o2.w*inv};
    float4 w3 = {o3.x*inv, o3.y*inv, o3.z*inv, o3.w*inv};
    op[0] = w0; op[1] = w1; op[2] = w2; op[3] = w3;
}

extern "C" void kernel_launch(void* const* d_in, const int* in_sizes, int n_in,
                              void* d_out, int out_size, void* d_ws, size_t ws_size,
                              hipStream_t stream) {
    const float* x  = (const float*)d_in[0];
    const float* Wk = (const float*)d_in[1];
    const float* Wq = (const float*)d_in[2];
    const float* Wv = (const float*)d_in[3];
    float* out = (float*)d_out;
    float* ws  = (float*)d_ws;

    const int M = in_sizes[0] / EMBED;   // B*T = 32768
    const int B = 8;
    const int T = M / B;                 // 4096

    float* kw = ws;
    float* qw = ws + (size_t)M * HD;
    float* vw = ws + 2 * (size_t)M * HD;

    qkv_proj<<<M / PROJ_ROWS, 256, 0, stream>>>(x, Wk, Wq, Wv, kw, qw, vw);
    dim3 g(T / QBLK, B);
    attn<<<g, 256, 0, stream>>>(kw, qw, vw, out, T);
}

// Round 2
// 297.274 us; speedup vs baseline: 3.9494x; 3.9494x over previous
//
#include <hip/hip_runtime.h>
#include <hip/hip_bf16.h>
#include <math.h>

#define EMBED 384
#define HD 64
#define QBLK 64   // q rows per attn block (4 waves x 16 rows)
#define KBLK 64   // keys per LDS tile
#define PROJ_ROWS 16

typedef unsigned short u16;
using bf16x8 = __attribute__((ext_vector_type(8))) __bf16;
using f32x4  = __attribute__((ext_vector_type(4))) float;

__device__ inline u16 f2bf(float f) {
    union { float f; unsigned u; } v; v.f = f;
    unsigned r = v.u + 0x7fffu + ((v.u >> 16) & 1u);
    return (u16)(r >> 16);
}
__device__ inline bf16x8 ld16(const u16* p) { return *(const bf16x8*)p; }

// ---------------- Projection: bf16 q (pre-scaled), bf16 k, bf16 v^T ----------------
__global__ __launch_bounds__(256) void qkv_proj(
    const float* __restrict__ x,
    const float* __restrict__ Wk, const float* __restrict__ Wq,
    const float* __restrict__ Wv,
    u16* __restrict__ kb, u16* __restrict__ qb, u16* __restrict__ vtb, int T)
{
    __shared__ float xs[PROJ_ROWS * EMBED];   // 24 KB
    const int base = blockIdx.x * PROJ_ROWS;
    const float4* xsrc = (const float4*)(x + (size_t)base * EMBED);
    for (int i = threadIdx.x; i < PROJ_ROWS * EMBED / 4; i += 256)
        ((float4*)xs)[i] = xsrc[i];
    __syncthreads();

    const int h  = threadIdx.x & 63;
    const int rg = threadIdx.x >> 6;          // 0..3 -> rows rg*4..rg*4+3
    float ak[4] = {0,0,0,0}, aq[4] = {0,0,0,0}, av[4] = {0,0,0,0};
    const float4* xr = (const float4*)(xs + rg * 4 * EMBED);

    #pragma unroll 2
    for (int c4 = 0; c4 < EMBED / 4; ++c4) {
        float4 xv[4];
        #pragma unroll
        for (int r = 0; r < 4; ++r) xv[r] = xr[r * (EMBED/4) + c4];
        const int c = c4 * 4;
        #pragma unroll
        for (int cc = 0; cc < 4; ++cc) {
            const float wk = Wk[(c + cc) * HD + h];
            const float wq = Wq[(c + cc) * HD + h];
            const float wv = Wv[(c + cc) * HD + h];
            #pragma unroll
            for (int r = 0; r < 4; ++r) {
                const float xvv = (cc == 0) ? xv[r].x : (cc == 1) ? xv[r].y
                                : (cc == 2) ? xv[r].z : xv[r].w;
                ak[r] = fmaf(xvv, wk, ak[r]);
                aq[r] = fmaf(xvv, wq, aq[r]);
                av[r] = fmaf(xvv, wv, av[r]);
            }
        }
    }
    const float qscale = 0.051031036307982884f;  // 1/sqrt(384)
    const int b = base / T;                      // block never straddles batch (T%16==0)
    const int trow = base - b * T + rg * 4;
    #pragma unroll
    for (int r = 0; r < 4; ++r) {
        const size_t row = (size_t)base + rg * 4 + r;
        kb[row * HD + h] = f2bf(ak[r]);
        qb[row * HD + h] = f2bf(aq[r] * qscale);
    }
    ushort4 vp;
    vp.x = f2bf(av[0]); vp.y = f2bf(av[1]); vp.z = f2bf(av[2]); vp.w = f2bf(av[3]);
    *(ushort4*)(vtb + (size_t)b * HD * T + (size_t)h * T + trow) = vp;
}

// ------------- stage 64x(128B) tile into LDS, XOR-swizzled source, linear dest -------------
__device__ inline void stage_tile(const u16* g0, int rstride, u16* lds, int wave, int lane)
{
    #pragma unroll
    for (int i = 0; i < 2; ++i) {
        const int chunk = ((wave * 2 + i) << 6) | lane;   // 0..511 (16B chunks)
        const int row = chunk >> 3;
        const int sc = (chunk & 7) ^ (row & 7);           // pre-swizzled source chunk
        const u16* src = g0 + (size_t)row * rstride + sc * 8;
        u16* dst = lds + ((wave * 2 + i) << 9);           // wave-uniform, +lane*16B by HW
        __builtin_amdgcn_global_load_lds(
            (const __attribute__((address_space(1))) void*)src,
            (__attribute__((address_space(3))) void*)dst, 16, 0, 0);
    }
}

// ---------------- Flash attention, bf16 MFMA 16x16x32 ----------------
// grid (T/QBLK, B), block 256 = 4 waves. Wave w owns q rows qstart+w*16..+15.
__global__ __launch_bounds__(256) void attn_mfma(
    const u16* __restrict__ qb, const u16* __restrict__ kb,
    const u16* __restrict__ vtb, float* __restrict__ out, int T)
{
    __shared__ u16 ks[2][KBLK * HD];   // 8 KB x2, [key][dim] swizzled
    __shared__ u16 vs[2][KBLK * HD];   // 8 KB x2, [dim][key] swizzled
    __shared__ u16 ps[4][16 * HD];     // per-wave P, 2 KB each, swizzled

    const int b      = blockIdx.y;
    const int qtile  = gridDim.x - 1 - blockIdx.x;   // heaviest first
    const int qstart = qtile * QBLK;
    const int wave = threadIdx.x >> 6;
    const int lane = threadIdx.x & 63;
    const int lr = lane & 15;          // 16-index (A-row / B-col / D-col)
    const int g  = lane >> 4;          // 0..3  (k-group / D-row-group)

    // Q A-frags: A[i=lr][k=g*8+j (+32)]
    const u16* qrow = qb + ((size_t)b * T + qstart + wave * 16 + lr) * HD + g * 8;
    const bf16x8 qf0 = ld16(qrow);
    const bf16x8 qf1 = ld16(qrow + 32);

    f32x4 o[4];
    #pragma unroll
    for (int d = 0; d < 4; ++d) o[d] = (f32x4){0.f,0.f,0.f,0.f};
    float m[4]    = {-INFINITY, -INFINITY, -INFINITY, -INFINITY};
    float lsum[4] = {0.f, 0.f, 0.f, 0.f};

    const u16* kbase  = kb  + (size_t)b * T * HD;
    const u16* vtbase = vtb + (size_t)b * HD * T;
    u16* pw = ps[wave];

    const int nt = qtile + 1;   // K-tiles of 64 (causal)
    stage_tile(kbase,  HD, ks[0], wave, lane);
    stage_tile(vtbase, T,  vs[0], wave, lane);
    __syncthreads();

    int cur = 0;
    for (int t = 0; t < nt; ++t) {
        const int kst = t * KBLK;
        if (t + 1 < nt) {   // prefetch next tile into other buffer (in flight during compute)
            stage_tile(kbase + (size_t)(kst + KBLK) * HD, HD, ks[cur ^ 1], wave, lane);
            stage_tile(vtbase + (kst + KBLK),             T,  vs[cur ^ 1], wave, lane);
        }
        const u16* kt = ks[cur];
        const u16* vt = vs[cur];

        // ---- QK^T: 4 key-subtiles of 16 ----
        f32x4 sc[4];
        #pragma unroll
        for (int s = 0; s < 4; ++s) {
            const int row = s * 16 + lr;          // key (B-col = lr)
            const int sw = row & 7;
            const bf16x8 k0 = ld16(kt + row * HD + ((g ^ sw) * 8));
            const bf16x8 k1 = ld16(kt + row * HD + (((g + 4) ^ sw) * 8));
            f32x4 acc = (f32x4){0.f,0.f,0.f,0.f};
            acc = __builtin_amdgcn_mfma_f32_16x16x32_bf16(qf0, k0, acc, 0, 0, 0);
            acc = __builtin_amdgcn_mfma_f32_16x16x32_bf16(qf1, k1, acc, 0, 0, 0);
            sc[s] = acc;   // S[row=g*4+r][key=kst+s*16+lr]
        }

        // ---- causal mask (diagonal tile only) ----
        if (kst == qstart) {
            #pragma unroll
            for (int s = 0; s < 4; ++s) {
                const int key = s * 16 + lr;
                #pragma unroll
                for (int r = 0; r < 4; ++r) {
                    const int row = wave * 16 + g * 4 + r;
                    if (key > row) sc[s][r] = -INFINITY;
                }
            }
        }

        // ---- row max over 64 keys ----
        float tmax[4];
        #pragma unroll
        for (int r = 0; r < 4; ++r) {
            float v = fmaxf(fmaxf(sc[0][r], sc[1][r]), fmaxf(sc[2][r], sc[3][r]));
            v = fmaxf(v, __shfl_xor(v, 1));
            v = fmaxf(v, __shfl_xor(v, 2));
            v = fmaxf(v, __shfl_xor(v, 4));
            v = fmaxf(v, __shfl_xor(v, 8));
            tmax[r] = v;
        }
        // ---- deferred rescale (THR=8) ----
        bool need = false;
        #pragma unroll
        for (int r = 0; r < 4; ++r) need = need || (tmax[r] > m[r] + 8.0f);
        if (__any((int)need)) {
            #pragma unroll
            for (int r = 0; r < 4; ++r) {
                const float mn = fmaxf(m[r], tmax[r]);
                const float corr = __expf(m[r] - mn);
                m[r] = mn;
                lsum[r] *= corr;
                #pragma unroll
                for (int d = 0; d < 4; ++d) o[d][r] *= corr;
            }
        }
        // ---- P = exp(S-m): write bf16 to per-wave swizzled LDS; accumulate row sums ----
        float psum[4] = {0.f,0.f,0.f,0.f};
        #pragma unroll
        for (int s = 0; s < 4; ++s) {
            const int col = s * 16 + lr;
            const int chunkc = col >> 3;
            #pragma unroll
            for (int r = 0; r < 4; ++r) {
                const float p = __expf(sc[s][r] - m[r]);
                psum[r] += p;
                const int row = g * 4 + r;
                pw[row * HD + ((chunkc ^ (row & 7)) * 8) + (col & 7)] = f2bf(p);
            }
        }
        #pragma unroll
        for (int r = 0; r < 4; ++r) {
            float v = psum[r];
            v += __shfl_xor(v, 1);
            v += __shfl_xor(v, 2);
            v += __shfl_xor(v, 4);
            v += __shfl_xor(v, 8);
            lsum[r] += v;
        }

        // ---- PV: O += P * V ----
        {
            const int prow = lr;               // A-row = q-row
            const int sw = prow & 7;
            const bf16x8 pa0 = ld16(pw + prow * HD + ((g ^ sw) * 8));
            const bf16x8 pa1 = ld16(pw + prow * HD + (((g + 4) ^ sw) * 8));
            #pragma unroll
            for (int d = 0; d < 4; ++d) {
                const int vrow = d * 16 + lr;  // B-col = dim
                const int vw = vrow & 7;
                const bf16x8 vb0 = ld16(vt + vrow * HD + ((g ^ vw) * 8));
                const bf16x8 vb1 = ld16(vt + vrow * HD + (((g + 4) ^ vw) * 8));
                o[d] = __builtin_amdgcn_mfma_f32_16x16x32_bf16(pa0, vb0, o[d], 0, 0, 0);
                o[d] = __builtin_amdgcn_mfma_f32_16x16x32_bf16(pa1, vb1, o[d], 0, 0, 0);
            }
        }
        __syncthreads();   // drains prefetch vmcnt + protects buffer swap
        cur ^= 1;
    }

    float inv[4];
    #pragma unroll
    for (int r = 0; r < 4; ++r) inv[r] = 1.0f / lsum[r];
    #pragma unroll
    for (int d = 0; d < 4; ++d) {
        #pragma unroll
        for (int r = 0; r < 4; ++r) {
            const int row = qstart + wave * 16 + g * 4 + r;
            out[((size_t)b * T + row) * HD + d * 16 + lr] = o[d][r] * inv[r];
        }
    }
}

extern "C" void kernel_launch(void* const* d_in, const int* in_sizes, int n_in,
                              void* d_out, int out_size, void* d_ws, size_t ws_size,
                              hipStream_t stream) {
    const float* x  = (const float*)d_in[0];
    const float* Wk = (const float*)d_in[1];
    const float* Wq = (const float*)d_in[2];
    const float* Wv = (const float*)d_in[3];
    float* out = (float*)d_out;

    const int M = in_sizes[0] / EMBED;   // B*T = 32768
    const int B = 8;
    const int T = M / B;                 // 4096

    u16* kb  = (u16*)d_ws;
    u16* qb  = kb + (size_t)M * HD;
    u16* vtb = qb + (size_t)M * HD;      // [B][HD][T]

    qkv_proj<<<M / PROJ_ROWS, 256, 0, stream>>>(x, Wk, Wq, Wv, kb, qb, vtb, T);
    dim3 g(T / QBLK, B);
    attn_mfma<<<g, 256, 0, stream>>>(qb, kb, vtb, out, T);
}

// Round 3
// 247.547 us; speedup vs baseline: 4.7428x; 1.2009x over previous
//
#include <hip/hip_runtime.h>
#include <hip/hip_bf16.h>
#include <math.h>

#define EMBED 384
#define HD 64
#define KBLK 64

typedef unsigned short u16;
typedef unsigned int u32;
using bf16x8 = __attribute__((ext_vector_type(8))) __bf16;
using f32x16 = __attribute__((ext_vector_type(16))) float;

__device__ inline u16 f2bf(float f) {
    union { float f; unsigned u; } v; v.f = f;
    unsigned r = v.u + 0x7fffu + ((v.u >> 16) & 1u);
    return (u16)(r >> 16);
}
__device__ inline bf16x8 ld16(const u16* p) { return *(const bf16x8*)p; }
__device__ inline u32 cvtpk(float lo, float hi) {
    u32 r;
    asm("v_cvt_pk_bf16_f32 %0, %1, %2" : "=v"(r) : "v"(lo), "v"(hi));
    return r;
}

// ---------------- Wt convert: [192 outcols][384 k] bf16; Wq gets qscale*log2e ----------------
__global__ __launch_bounds__(256) void wconv(
    const float* __restrict__ Wk, const float* __restrict__ Wq,
    const float* __restrict__ Wv, u16* __restrict__ Wt)
{
    const int idx = blockIdx.x * 256 + threadIdx.x;
    if (idx >= 192 * EMBED) return;
    const int col = idx / EMBED, k = idx - col * EMBED;
    const int mat = col >> 6, c2 = col & 63;
    const float* W = (mat == 0) ? Wk : (mat == 1) ? Wq : Wv;
    float v = W[k * HD + c2];
    if (mat == 1) v *= 0.051031036307982884f * 1.4426950408889634f;  // 1/sqrt(384)*log2e
    Wt[idx] = f2bf(v);
}

// ---------------- Projection GEMM (swapped): D[outcol][token], col=token ----------------
// 1-wave blocks, 32 tokens each. acc[6] = 6 outcol-groups of 32 (K0,K1,Q0,Q1,V0,V1).
__global__ __launch_bounds__(64, 1) void proj_mfma(
    const float* __restrict__ x, const u16* __restrict__ Wt,
    u16* __restrict__ kb, u16* __restrict__ qb, u16* __restrict__ vtb, int T)
{
    const int lane = threadIdx.x;
    const int c = lane & 31, h = lane >> 5;
    const int tok = blockIdx.x * 32 + c;
    const float* xr = x + (size_t)tok * EMBED + 8 * h;

    f32x16 acc[6];
    #pragma unroll
    for (int g = 0; g < 6; ++g)
        #pragma unroll
        for (int r = 0; r < 16; ++r) acc[g][r] = 0.f;

    float4 xa0 = *(const float4*)(xr);
    float4 xb0 = *(const float4*)(xr + 4);
    float4 xa1 = *(const float4*)(xr + 16);
    float4 xb1 = *(const float4*)(xr + 20);

    for (int kk = 0; kk < 24; ++kk) {
        float4 xan = xa1, xbn = xb1;
        if (kk < 22) {
            xan = *(const float4*)(xr + (kk + 2) * 16);
            xbn = *(const float4*)(xr + (kk + 2) * 16 + 4);
        }
        union { u32 u[4]; bf16x8 v; } bf;
        bf.u[0] = cvtpk(xa0.x, xa0.y); bf.u[1] = cvtpk(xa0.z, xa0.w);
        bf.u[2] = cvtpk(xb0.x, xb0.y); bf.u[3] = cvtpk(xb0.z, xb0.w);
        #pragma unroll
        for (int g = 0; g < 6; ++g) {
            const bf16x8 wf = ld16(Wt + (size_t)(g * 32 + c) * EMBED + kk * 16 + 8 * h);
            acc[g] = __builtin_amdgcn_mfma_f32_32x32x16_bf16(wf, bf.v, acc[g], 0, 0, 0);
        }
        xa0 = xa1; xb0 = xb1; xa1 = xan; xb1 = xbn;
    }

    // K, Q: row-major [token][64]; regs 4k2..4k2+3 -> outcols 8k2+4h+0..3
    #pragma unroll
    for (int mat = 0; mat < 2; ++mat) {
        u16* dst = (mat == 0) ? kb : qb;
        #pragma unroll
        for (int dg = 0; dg < 2; ++dg) {
            const f32x16 a = acc[mat * 2 + dg];
            #pragma unroll
            for (int k2 = 0; k2 < 4; ++k2) {
                u32 pair[2];
                pair[0] = cvtpk(a[4 * k2], a[4 * k2 + 1]);
                pair[1] = cvtpk(a[4 * k2 + 2], a[4 * k2 + 3]);
                *(uint2*)(dst + (size_t)tok * HD + dg * 32 + 8 * k2 + 4 * h) = *(uint2*)pair;
            }
        }
    }
    // V^T: [b][dim][T]
    const int bb = tok / T, trow = tok - bb * T;
    u16* vb = vtb + (size_t)bb * HD * T + trow;
    #pragma unroll
    for (int dg = 0; dg < 2; ++dg) {
        const f32x16 a = acc[4 + dg];
        #pragma unroll
        for (int r = 0; r < 16; ++r) {
            const int dim = (r & 3) + 8 * (r >> 2) + 4 * h + 32 * dg;
            vb[(size_t)dim * T] = f2bf(a[r]);
        }
    }
}

// ------------- stage 64x(128B) tile into LDS, XOR-swizzled source, linear dest -------------
__device__ inline void stage_tile(const u16* g0, int rstride, u16* lds, int wave, int lane)
{
    #pragma unroll
    for (int i = 0; i < 2; ++i) {
        const int chunk = ((wave * 2 + i) << 6) | lane;   // 0..511 (16B chunks)
        const int row = chunk >> 3;
        const int sc = (chunk & 7) ^ (row & 7);           // pre-swizzled source chunk
        const u16* src = g0 + (size_t)row * rstride + sc * 8;
        u16* dst = lds + ((wave * 2 + i) << 9);
        __builtin_amdgcn_global_load_lds(
            (const __attribute__((address_space(1))) void*)src,
            (__attribute__((address_space(3))) void*)dst, 16, 0, 0);
    }
}

// ---------------- Flash attention: 32x32 double-swapped, in-register softmax ----------------
// grid (8 batches, T/128 qtiles heavy-first), block 256 = 4 waves x 32 q-rows.
// S^T = mfma(K, Q): col = qrow (softmax state per-lane). O^T = mfma(V^T, P^T): col = qrow.
__global__ __launch_bounds__(256, 1) void attn_mfma(
    const u16* __restrict__ qb, const u16* __restrict__ kb,
    const u16* __restrict__ vtb, float* __restrict__ out, int T)
{
    __shared__ u16 ks[2][KBLK * HD];   // [key][dim], chunk-swizzled
    __shared__ u16 vs[2][KBLK * HD];   // [dim][key], chunk-swizzled

    const int b     = blockIdx.x;                    // XCD id == batch
    const int qtile = gridDim.y - 1 - blockIdx.y;    // heavy first
    const int qs    = qtile * 128;
    const int wv   = threadIdx.x >> 6;
    const int lane = threadIdx.x & 63;
    const int c = lane & 31, h = lane >> 5;
    const int qrow = qs + 32 * wv + c;

    // Q B-frags (scores in log2 units; scale folded into Wq)
    bf16x8 qf[4];
    const u16* qp = qb + ((size_t)b * T + qrow) * HD + 8 * h;
    #pragma unroll
    for (int kk = 0; kk < 4; ++kk) qf[kk] = ld16(qp + kk * 16);

    f32x16 o0, o1;
    #pragma unroll
    for (int r = 0; r < 16; ++r) { o0[r] = 0.f; o1[r] = 0.f; }
    float m = -INFINITY, lsum = 0.f;

    const u16* kbase  = kb  + (size_t)b * T * HD;
    const u16* vtbase = vtb + (size_t)b * HD * T;

    const int nsub  = 4 * qtile + wv + 1;   // this wave's 32-key subtile count
    const int ntile = 2 * qtile + 2;        // block KBLK-tiles

    stage_tile(kbase,  HD, ks[0], wv, lane);
    stage_tile(vtbase, T,  vs[0], wv, lane);
    __syncthreads();

    int cur = 0;
    for (int tt = 0; tt < ntile; ++tt) {
        if (tt + 1 < ntile) {
            stage_tile(kbase + (size_t)(tt + 1) * KBLK * HD, HD, ks[cur ^ 1], wv, lane);
            stage_tile(vtbase + (tt + 1) * KBLK,             T,  vs[cur ^ 1], wv, lane);
        }
        const u16* kt = ks[cur];
        const u16* vt = vs[cur];

        #pragma unroll
        for (int sub = 0; sub < 2; ++sub) {
            const int gs = tt * 2 + sub;
            if (gs < nsub) {
                // ---- QK^T: S^T[key 32][qrow 32] over K=64 dims ----
                f32x16 st;
                #pragma unroll
                for (int r = 0; r < 16; ++r) st[r] = 0.f;
                const int krow = 32 * sub + c;
                #pragma unroll
                for (int kk = 0; kk < 4; ++kk) {
                    const bf16x8 kf = ld16(kt + krow * HD + (((2 * kk + h) ^ (krow & 7)) * 8));
                    st = __builtin_amdgcn_mfma_f32_32x32x16_bf16(kf, qf[kk], st, 0, 0, 0);
                }
                // ---- causal mask (diagonal subtile only: key base == wave row base) ----
                if (gs == nsub - 1) {
                    #pragma unroll
                    for (int r = 0; r < 16; ++r) {
                        const int key = (r & 3) + 8 * (r >> 2) + 4 * h;
                        if (key > c) st[r] = -INFINITY;
                    }
                }
                // ---- row max (in-lane 16 + cross-half) ----
                float tm = st[0];
                #pragma unroll
                for (int r = 1; r < 16; ++r) tm = fmaxf(tm, st[r]);
                tm = fmaxf(tm, __shfl_xor(tm, 32));
                // ---- deferred rescale (THR = 8/ln2 in log2 units) ----
                if (__any(tm > m + 11.5f)) {
                    const float mn = fmaxf(m, tm);
                    const float corr = exp2f(m - mn);
                    m = mn;
                    lsum *= corr;
                    #pragma unroll
                    for (int r = 0; r < 16; ++r) { o0[r] *= corr; o1[r] *= corr; }
                }
                // ---- P = 2^(S-m), row sums ----
                float p[16];
                float ps = 0.f;
                #pragma unroll
                for (int r = 0; r < 16; ++r) { p[r] = exp2f(st[r] - m); ps += p[r]; }
                lsum += ps + __shfl_xor(ps, 32);
                // ---- pack P -> bf16, exchange halves, PV ----
                u32 w[8];
                #pragma unroll
                for (int q = 0; q < 8; ++q) w[q] = cvtpk(p[2 * q], p[2 * q + 1]);
                #pragma unroll
                for (int ks2 = 0; ks2 < 2; ++ks2) {
                    const u32 x0 = __shfl_xor(w[4 * ks2 + 0], 32);
                    const u32 x1 = __shfl_xor(w[4 * ks2 + 1], 32);
                    const u32 x2 = __shfl_xor(w[4 * ks2 + 2], 32);
                    const u32 x3 = __shfl_xor(w[4 * ks2 + 3], 32);
                    union { u32 u[4]; bf16x8 v; } pf;
                    if (h == 0) { pf.u[0] = w[4*ks2];   pf.u[1] = w[4*ks2+1]; pf.u[2] = x0; pf.u[3] = x1; }
                    else        { pf.u[0] = x2;         pf.u[1] = x3;         pf.u[2] = w[4*ks2+2]; pf.u[3] = w[4*ks2+3]; }
                    // dims 0..31
                    {
                        const bf16x8 vf = ld16(vt + c * KBLK + (((4 * sub + 2 * ks2 + h) ^ (c & 7)) * 8));
                        o0 = __builtin_amdgcn_mfma_f32_32x32x16_bf16(vf, pf.v, o0, 0, 0, 0);
                    }
                    // dims 32..63
                    {
                        const int drow = 32 + c;
                        const bf16x8 vf = ld16(vt + drow * KBLK + (((4 * sub + 2 * ks2 + h) ^ (drow & 7)) * 8));
                        o1 = __builtin_amdgcn_mfma_f32_32x32x16_bf16(vf, pf.v, o1, 0, 0, 0);
                    }
                }
            }
        }
        __syncthreads();
        cur ^= 1;
    }

    // ---- epilogue: O^T regs -> out[b][qrow][dim], f32 ----
    const float inv = 1.f / lsum;
    float* op = out + ((size_t)b * T + qrow) * HD;
    #pragma unroll
    for (int k2 = 0; k2 < 4; ++k2) {
        float4 s0, s1;
        s0.x = o0[4*k2] * inv;   s0.y = o0[4*k2+1] * inv;
        s0.z = o0[4*k2+2] * inv; s0.w = o0[4*k2+3] * inv;
        s1.x = o1[4*k2] * inv;   s1.y = o1[4*k2+1] * inv;
        s1.z = o1[4*k2+2] * inv; s1.w = o1[4*k2+3] * inv;
        *(float4*)(op + 8 * k2 + 4 * h)      = s0;
        *(float4*)(op + 32 + 8 * k2 + 4 * h) = s1;
    }
}

extern "C" void kernel_launch(void* const* d_in, const int* in_sizes, int n_in,
                              void* d_out, int out_size, void* d_ws, size_t ws_size,
                              hipStream_t stream) {
    const float* x  = (const float*)d_in[0];
    const float* Wk = (const float*)d_in[1];
    const float* Wq = (const float*)d_in[2];
    const float* Wv = (const float*)d_in[3];
    float* out = (float*)d_out;

    const int M = in_sizes[0] / EMBED;   // B*T = 32768
    const int B = 8;
    const int T = M / B;                 // 4096

    u16* kb  = (u16*)d_ws;
    u16* qb  = kb + (size_t)M * HD;
    u16* vtb = qb + (size_t)M * HD;              // [B][HD][T]
    u16* Wt  = vtb + (size_t)M * HD;             // [192][384]

    wconv<<<(192 * EMBED + 255) / 256, 256, 0, stream>>>(Wk, Wq, Wv, Wt);
    proj_mfma<<<M / 32, 64, 0, stream>>>(x, Wt, kb, qb, vtb, T);
    dim3 g(B, T / 128);
    attn_mfma<<<g, 256, 0, stream>>>(qb, kb, vtb, out, T);
}

// Round 4
// 184.064 us; speedup vs baseline: 6.3785x; 1.3449x over previous
//
#include <hip/hip_runtime.h>
#include <hip/hip_bf16.h>
#include <math.h>

#define EMBED 384
#define HD 64

typedef unsigned short u16;
typedef unsigned int u32;
using bf16x8 = __attribute__((ext_vector_type(8))) __bf16;
using f32x16 = __attribute__((ext_vector_type(16))) float;

__device__ inline u16 f2bf(float f) {
    union { float f; unsigned u; } v; v.f = f;
    unsigned r = v.u + 0x7fffu + ((v.u >> 16) & 1u);
    return (u16)(r >> 16);
}
__device__ inline bf16x8 ld16(const u16* p) { return *(const bf16x8*)p; }
__device__ inline u32 cvtpk(float lo, float hi) {
    u32 r;
    asm("v_cvt_pk_bf16_f32 %0, %1, %2" : "=v"(r) : "v"(lo), "v"(hi));
    return r;
}

// ---------------- Wt convert: [192 outcols][384 k] bf16; Wq gets qscale*log2e ----------------
__global__ __launch_bounds__(256) void wconv(
    const float* __restrict__ Wk, const float* __restrict__ Wq,
    const float* __restrict__ Wv, u16* __restrict__ Wt)
{
    const int idx = blockIdx.x * 256 + threadIdx.x;
    if (idx >= 192 * EMBED) return;
    const int col = idx / EMBED, k = idx - col * EMBED;
    const int mat = col >> 6, c2 = col & 63;
    const float* W = (mat == 0) ? Wk : (mat == 1) ? Wq : Wv;
    float v = W[k * HD + c2];
    if (mat == 1) v *= 0.051031036307982884f * 1.4426950408889634f;  // 1/sqrt(384)*log2e
    Wt[idx] = f2bf(v);
}

// ---------------- Projection GEMM (swapped): D[outcol][token], col=token ----------------
// 1-wave blocks, 32 tokens. x prefetch 4 deep, Wt frags double-buffered.
#define PSTEP(kk, XA, XB, WCUR, WNXT)                                          \
  {                                                                            \
    union { u32 u[4]; bf16x8 v; } bf;                                          \
    bf.u[0] = cvtpk(XA.x, XA.y); bf.u[1] = cvtpk(XA.z, XA.w);                  \
    bf.u[2] = cvtpk(XB.x, XB.y); bf.u[3] = cvtpk(XB.z, XB.w);                  \
    if ((kk) + 1 < 24) {                                                       \
      _Pragma("unroll")                                                        \
      for (int g = 0; g < 6; ++g)                                              \
        WNXT[g] = ld16(wb + (size_t)g * 32 * EMBED + ((kk) + 1) * 16);         \
    }                                                                          \
    _Pragma("unroll")                                                          \
    for (int g = 0; g < 6; ++g)                                                \
      acc[g] = __builtin_amdgcn_mfma_f32_32x32x16_bf16(WCUR[g], bf.v, acc[g], 0, 0, 0); \
    if ((kk) + 4 < 24) {                                                       \
      XA = *(const float4*)(xr + ((kk) + 4) * 16);                             \
      XB = *(const float4*)(xr + ((kk) + 4) * 16 + 4);                         \
    }                                                                          \
  }

__global__ __launch_bounds__(64) void proj_mfma(
    const float* __restrict__ x, const u16* __restrict__ Wt,
    u16* __restrict__ kb, u16* __restrict__ qb, u16* __restrict__ vtb, int T)
{
    const int lane = threadIdx.x;
    const int c = lane & 31, h = lane >> 5;
    const int tok = blockIdx.x * 32 + c;
    const float* xr = x + (size_t)tok * EMBED + 8 * h;
    const u16* wb = Wt + (size_t)c * EMBED + 8 * h;

    f32x16 acc[6];
    #pragma unroll
    for (int g = 0; g < 6; ++g)
        #pragma unroll
        for (int r = 0; r < 16; ++r) acc[g][r] = 0.f;

    float4 x0a = *(const float4*)(xr);
    float4 x0b = *(const float4*)(xr + 4);
    float4 x1a = *(const float4*)(xr + 16);
    float4 x1b = *(const float4*)(xr + 20);
    float4 x2a = *(const float4*)(xr + 32);
    float4 x2b = *(const float4*)(xr + 36);
    float4 x3a = *(const float4*)(xr + 48);
    float4 x3b = *(const float4*)(xr + 52);

    bf16x8 wfA[6], wfB[6];
    #pragma unroll
    for (int g = 0; g < 6; ++g) wfA[g] = ld16(wb + (size_t)g * 32 * EMBED);

    for (int k4 = 0; k4 < 24; k4 += 4) {
        PSTEP(k4 + 0, x0a, x0b, wfA, wfB)
        PSTEP(k4 + 1, x1a, x1b, wfB, wfA)
        PSTEP(k4 + 2, x2a, x2b, wfA, wfB)
        PSTEP(k4 + 3, x3a, x3b, wfB, wfA)
    }

    // K, Q: row-major [token][64]
    #pragma unroll
    for (int mat = 0; mat < 2; ++mat) {
        u16* dst = (mat == 0) ? kb : qb;
        #pragma unroll
        for (int dg = 0; dg < 2; ++dg) {
            const f32x16 a = acc[mat * 2 + dg];
            #pragma unroll
            for (int k2 = 0; k2 < 4; ++k2) {
                u32 pair[2];
                pair[0] = cvtpk(a[4 * k2], a[4 * k2 + 1]);
                pair[1] = cvtpk(a[4 * k2 + 2], a[4 * k2 + 3]);
                *(uint2*)(dst + (size_t)tok * HD + dg * 32 + 8 * k2 + 4 * h) = *(uint2*)pair;
            }
        }
    }
    // V^T: [b][dim][T]
    const int bb = tok / T, trow = tok - bb * T;
    u16* vb = vtb + (size_t)bb * HD * T + trow;
    #pragma unroll
    for (int dg = 0; dg < 2; ++dg) {
        const f32x16 a = acc[4 + dg];
        #pragma unroll
        for (int r = 0; r < 16; ++r) {
            const int dim = (r & 3) + 8 * (r >> 2) + 4 * h + 32 * dg;
            vb[(size_t)dim * T] = f2bf(a[r]);
        }
    }
}

// ---------------- Flash attention: 32-row qtiles, 4-way key-split block ----------------
// grid (8 batches, T/32 qtiles heavy-first), block 256 = 4 waves, all on same 32 q-rows.
// Wave w handles key-subtiles s = w, w+4, ... (32 keys each), direct L2 reads, no staging.
// S^T = mfma(K, Q): col = qrow (per-lane softmax state). O^T = mfma(V^T, P^T).
__global__ __launch_bounds__(256) void attn_mfma(
    const u16* __restrict__ qb, const u16* __restrict__ kb,
    const u16* __restrict__ vtb, float* __restrict__ out, int T)
{
    __shared__ float slab[4][HD][32];   // 32 KB, [wave][dim][row]
    __shared__ float ml2[2][4][32];     // [m|l][wave][row]
    __shared__ float linv_s[32];

    const int b    = blockIdx.x;                     // batch == XCD slot
    const int q32  = gridDim.y - 1 - blockIdx.y;     // heavy first
    const int qs   = q32 * 32;
    const int wv   = threadIdx.x >> 6;
    const int lane = threadIdx.x & 63;
    const int c = lane & 31, h = lane >> 5;

    // Q B-frags (log2-units: scale folded into Wq)
    bf16x8 qf[4];
    const u16* qp = qb + ((size_t)b * T + qs + c) * HD + 8 * h;
    #pragma unroll
    for (int kk = 0; kk < 4; ++kk) qf[kk] = ld16(qp + kk * 16);

    f32x16 o0, o1;
    #pragma unroll
    for (int r = 0; r < 16; ++r) { o0[r] = 0.f; o1[r] = 0.f; }
    float m = -INFINITY, lsum = 0.f;

    const u16* kbase  = kb  + (size_t)b * T * HD;
    const u16* vtbase = vtb + (size_t)b * HD * T;

    for (int s = wv; s <= q32; s += 4) {
        // ---- K frags: A[row=key][k=dim] ----
        const u16* kp = kbase + (size_t)(32 * s + c) * HD + 8 * h;
        bf16x8 kf0 = ld16(kp), kf1 = ld16(kp + 16), kf2 = ld16(kp + 32), kf3 = ld16(kp + 48);
        // ---- V frags (issued early): A[row=dim][k=key] ----
        const u16* vp = vtbase + (size_t)c * T + 32 * s + 8 * h;
        const bf16x8 vf00 = ld16(vp), vf01 = ld16(vp + 16);
        const u16* vp2 = vp + (size_t)32 * T;
        const bf16x8 vf10 = ld16(vp2), vf11 = ld16(vp2 + 16);

        // ---- QK^T over 64 dims ----
        f32x16 st;
        #pragma unroll
        for (int r = 0; r < 16; ++r) st[r] = 0.f;
        st = __builtin_amdgcn_mfma_f32_32x32x16_bf16(kf0, qf[0], st, 0, 0, 0);
        st = __builtin_amdgcn_mfma_f32_32x32x16_bf16(kf1, qf[1], st, 0, 0, 0);
        st = __builtin_amdgcn_mfma_f32_32x32x16_bf16(kf2, qf[2], st, 0, 0, 0);
        st = __builtin_amdgcn_mfma_f32_32x32x16_bf16(kf3, qf[3], st, 0, 0, 0);

        // ---- causal mask: only the global-diagonal subtile ----
        if (s == q32) {
            #pragma unroll
            for (int r = 0; r < 16; ++r) {
                const int key = (r & 3) + 8 * (r >> 2) + 4 * h;
                if (key > c) st[r] = -INFINITY;
            }
        }
        // ---- row max ----
        float tm = st[0];
        #pragma unroll
        for (int r = 1; r < 16; ++r) tm = fmaxf(tm, st[r]);
        tm = fmaxf(tm, __shfl_xor(tm, 32));
        // ---- deferred rescale (THR = 8/ln2) ----
        if (__any(tm > m + 11.5f)) {
            const float mn = fmaxf(m, tm);
            const float corr = exp2f(m - mn);
            m = mn;
            lsum *= corr;
            #pragma unroll
            for (int r = 0; r < 16; ++r) { o0[r] *= corr; o1[r] *= corr; }
        }
        // ---- P = 2^(S-m) (in place), row sums ----
        float ps = 0.f;
        #pragma unroll
        for (int r = 0; r < 16; ++r) { st[r] = exp2f(st[r] - m); ps += st[r]; }
        lsum += ps + __shfl_xor(ps, 32);
        // ---- pack P -> bf16, exchange halves, PV ----
        u32 w[8];
        #pragma unroll
        for (int q = 0; q < 8; ++q) w[q] = cvtpk(st[2 * q], st[2 * q + 1]);
        #pragma unroll
        for (int ks2 = 0; ks2 < 2; ++ks2) {
            const u32 x0 = __shfl_xor(w[4 * ks2 + 0], 32);
            const u32 x1 = __shfl_xor(w[4 * ks2 + 1], 32);
            const u32 x2 = __shfl_xor(w[4 * ks2 + 2], 32);
            const u32 x3 = __shfl_xor(w[4 * ks2 + 3], 32);
            union { u32 u[4]; bf16x8 v; } pf;
            if (h == 0) { pf.u[0] = w[4*ks2];   pf.u[1] = w[4*ks2+1]; pf.u[2] = x0; pf.u[3] = x1; }
            else        { pf.u[0] = x2;         pf.u[1] = x3;         pf.u[2] = w[4*ks2+2]; pf.u[3] = w[4*ks2+3]; }
            if (ks2 == 0) {
                o0 = __builtin_amdgcn_mfma_f32_32x32x16_bf16(vf00, pf.v, o0, 0, 0, 0);
                o1 = __builtin_amdgcn_mfma_f32_32x32x16_bf16(vf10, pf.v, o1, 0, 0, 0);
            } else {
                o0 = __builtin_amdgcn_mfma_f32_32x32x16_bf16(vf01, pf.v, o0, 0, 0, 0);
                o1 = __builtin_amdgcn_mfma_f32_32x32x16_bf16(vf11, pf.v, o1, 0, 0, 0);
            }
        }
    }

    // ---- cross-wave merge ----
    if (h == 0) { ml2[0][wv][c] = m; ml2[1][wv][c] = lsum; }
    __syncthreads();
    float M = -INFINITY;
    #pragma unroll
    for (int i = 0; i < 4; ++i) M = fmaxf(M, ml2[0][i][c]);
    float L = 0.f;
    #pragma unroll
    for (int i = 0; i < 4; ++i) L += ml2[1][i][c] * exp2f(ml2[0][i][c] - M);
    const float coef = exp2f(m - M);
    if (wv == 0 && h == 0) linv_s[c] = 1.f / L;
    #pragma unroll
    for (int r = 0; r < 16; ++r) {
        const int d0 = (r & 3) + 8 * (r >> 2) + 4 * h;
        slab[wv][d0][c]      = o0[r] * coef;
        slab[wv][d0 + 32][c] = o1[r] * coef;
    }
    __syncthreads();

    // ---- final: wave wv writes dims 16wv..16wv+15 of all 32 rows ----
    float res[8];
    #pragma unroll
    for (int j = 0; j < 8; ++j) {
        const int d = 16 * wv + 8 * h + j;
        res[j] = slab[0][d][c] + slab[1][d][c] + slab[2][d][c] + slab[3][d][c];
    }
    const float li = linv_s[c];
    float4 s0 = {res[0] * li, res[1] * li, res[2] * li, res[3] * li};
    float4 s1 = {res[4] * li, res[5] * li, res[6] * li, res[7] * li};
    float* op = out + ((size_t)b * T + qs + c) * HD + 16 * wv + 8 * h;
    *(float4*)op = s0;
    *(float4*)(op + 4) = s1;
}

extern "C" void kernel_launch(void* const* d_in, const int* in_sizes, int n_in,
                              void* d_out, int out_size, void* d_ws, size_t ws_size,
                              hipStream_t stream) {
    const float* x  = (const float*)d_in[0];
    const float* Wk = (const float*)d_in[1];
    const float* Wq = (const float*)d_in[2];
    const float* Wv = (const float*)d_in[3];
    float* out = (float*)d_out;

    const int M = in_sizes[0] / EMBED;   // B*T = 32768
    const int B = 8;
    const int T = M / B;                 // 4096

    u16* kb  = (u16*)d_ws;
    u16* qb  = kb + (size_t)M * HD;
    u16* vtb = qb + (size_t)M * HD;              // [B][HD][T]
    u16* Wt  = vtb + (size_t)M * HD;             // [192][384]

    wconv<<<(192 * EMBED + 255) / 256, 256, 0, stream>>>(Wk, Wq, Wv, Wt);
    proj_mfma<<<M / 32, 64, 0, stream>>>(x, Wt, kb, qb, vtb, T);
    dim3 g(B, T / 32);
    attn_mfma<<<g, 256, 0, stream>>>(qb, kb, vtb, out, T);
}